// Round 4
// baseline (286.333 us; speedup 1.0000x reference)
//
#include <hip/hip_runtime.h>

// out[r, i] = sum_{k=0..4} W[i,k] * x[r, i+k-2] + b[i], zero-padded at edges.
// B=8192 rows, C=4096 channels, K=5, fp32.
//
// R1: per-(row,channel) W loads -> L1/TA line-request bound.
// R2: thread owns 4 channels, W+bias in regs, loops rows. 91 us/dispatch.
// R3: 4096 blocks (16/CU backfill): occupancy 56->67%, 83 us. nt stores FAILED
//     (+12.5% WRITE, FETCH unchanged) -> reverted.
// R4: wave-edge-lane halo via __shfl: 83->~76 us (only 9% -> line-requests
//     were NOT the limiter).
// R5: VGPR_Count=32 exposed that the compiler DELETED the source-level
// distance-1 pipeline (true distance-1 needs ~44 live VGPRs: W=20+bv=4+cur=8+
// next=8+addr). Loads were sunk below the store -> every wave eats a full
// memory latency per row, serially. VALUBusy 6% and 2.7 B/cyc/CU match.
// Fix: explicit multi-buffer arrays with compile-time indices (full unroll),
// DEPTH=2 prologue, steady-state "load r+2, compute r". Liveness ~56 VGPR,
// still 8 waves/SIMD under __launch_bounds__(256,8).
// Verification hook: VGPR_Count must rise to ~56; if it stays 32 the theory
// is falsified.
// R6 (this): R5 bench was an infra failure (container acquisition failed
// twice, no counters) -> resubmitting identical kernel for measurement.

#define B_ROWS 8192
#define C_CH   4096
#define KWIN   5
#define ROWS_PER_BLOCK 8
#define NCHUNK (C_CH / 4)   // 1024 float4 chunks per row
#define DEPTH  2            // prefetch distance (rows in flight)

__global__ __launch_bounds__(256, 8) void grouped_linear_kernel(
    const float* __restrict__ x, const float* __restrict__ W,
    const float* __restrict__ bias, float* __restrict__ out)
{
    // chunk = which group of 4 channels this thread owns (0..1023)
    const int chunk = (blockIdx.x << 8) + threadIdx.x;   // gridDim.x == 4
    const int c     = chunk << 2;                        // base channel
    const int r0    = blockIdx.y * ROWS_PER_BLOCK;
    const int lane  = threadIdx.x & 63;

    // --- loop-invariant: W rows c..c+3 (20 contiguous floats) + bias ---
    const float4* W4 = (const float4*)(W + (size_t)c * KWIN);
    const float4 w0 = W4[0];  // W[c][0..3]
    const float4 w1 = W4[1];  // W[c][4], W[c+1][0..2]
    const float4 w2 = W4[2];  // W[c+1][3..4], W[c+2][0..1]
    const float4 w3 = W4[3];  // W[c+2][2..4], W[c+3][0]
    const float4 w4 = W4[4];  // W[c+3][1..4]
    const float4 bv = ((const float4*)bias)[chunk];

    const float4 zero = make_float4(0.f, 0.f, 0.f, 0.f);

    // Halo: only wave-edge lanes touch memory for it. Lane 0 needs chunk-1
    // (uses .z,.w), lane 63 needs chunk+1 (uses .x,.y). One masked load.
    const bool is_lo = (lane == 0);
    const bool is_hi = (lane == 63);
    const int  hchunk = is_lo ? (chunk - 1) : (chunk + 1);
    const bool hvalid = (is_lo && chunk > 0) || (is_hi && chunk + 1 < NCHUNK);

    const float4* xrow = (const float4*)(x   + (size_t)r0 * C_CH);
    float4*       orow = (float4*)      (out + (size_t)r0 * C_CH);
    const int rstride = C_CH / 4;

    // Explicit multi-buffer pipeline. All indices are compile-time constants
    // after full unroll, so these stay in registers (liveness = DEPTH+1 rows).
    float4 xb[ROWS_PER_BLOCK];
    float4 hb[ROWS_PER_BLOCK];

    #pragma unroll
    for (int p = 0; p < DEPTH; ++p) {
        const float4* rp = xrow + p * rstride;
        xb[p] = rp[chunk];
        hb[p] = zero;
        if (hvalid) hb[p] = rp[hchunk];
    }

    #pragma unroll
    for (int r = 0; r < ROWS_PER_BLOCK; ++r) {
        // issue loads for row r+DEPTH before consuming row r
        if (r + DEPTH < ROWS_PER_BLOCK) {
            const float4* rp = xrow + (r + DEPTH) * rstride;
            xb[r + DEPTH] = rp[chunk];
            hb[r + DEPTH] = zero;
            if (hvalid) hb[r + DEPTH] = rp[hchunk];
        }

        const float4 xc = xb[r];
        const float4 hl = hb[r];

        // halo via cross-lane: left neighbor's .z/.w, right neighbor's .x/.y
        const float mz = __shfl_up(xc.z, 1);
        const float mw = __shfl_up(xc.w, 1);
        const float px = __shfl_down(xc.x, 1);
        const float py = __shfl_down(xc.y, 1);

        // win[m] = x[r, c - 2 + m], m = 0..7
        const float win0 = is_lo ? hl.z : mz;
        const float win1 = is_lo ? hl.w : mw;
        const float win2 = xc.x, win3 = xc.y, win4 = xc.z, win5 = xc.w;
        const float win6 = is_hi ? hl.x : px;
        const float win7 = is_hi ? hl.y : py;

        float4 o;
        o.x = fmaf(w0.x, win0, fmaf(w0.y, win1, fmaf(w0.z, win2, fmaf(w0.w, win3, fmaf(w1.x, win4, bv.x)))));
        o.y = fmaf(w1.y, win1, fmaf(w1.z, win2, fmaf(w1.w, win3, fmaf(w2.x, win4, fmaf(w2.y, win5, bv.y)))));
        o.z = fmaf(w2.z, win2, fmaf(w2.w, win3, fmaf(w3.x, win4, fmaf(w3.y, win5, fmaf(w3.z, win6, bv.z)))));
        o.w = fmaf(w3.w, win3, fmaf(w4.x, win4, fmaf(w4.y, win5, fmaf(w4.z, win6, fmaf(w4.w, win7, bv.w)))));

        orow[chunk + r * rstride] = o;
    }
}

extern "C" void kernel_launch(void* const* d_in, const int* in_sizes, int n_in,
                              void* d_out, int out_size, void* d_ws, size_t ws_size,
                              hipStream_t stream) {
    const float* x    = (const float*)d_in[0];
    const float* W    = (const float*)d_in[1];
    const float* bias = (const float*)d_in[2];
    float* out = (float*)d_out;

    dim3 grid(C_CH / 4 / 256, B_ROWS / ROWS_PER_BLOCK);  // (4, 1024) = 4096 blocks
    dim3 block(256);
    grouped_linear_kernel<<<grid, block, 0, stream>>>(x, W, bias, out);
}

// Round 5
// 227.548 us; speedup vs baseline: 1.2583x; 1.2583x over previous
//
#include <hip/hip_runtime.h>

// out[r, i] = sum_{k=0..4} W[i,k] * x[r, i+k-2] + b[i], zero-padded at edges.
// B=8192 rows, C=4096 channels, K=5, fp32.
//
// R1: per-(row,channel) W loads -> L1/TA line-request bound.
// R2: thread owns 4 channels, W+bias in regs, loops rows. 91 us/dispatch.
// R3: 4096 blocks (16/CU backfill): occupancy 56->67%, 83 us. nt stores FAILED.
// R4: wave-edge halo via __shfl: ~76 us (only 9% -> line-requests not limiter).
// R5/R6: register software pipelines FAILED twice: compiler either sinks
//   loads to uses (VGPR=32, depth 0, one mem latency per row per wave) or
//   spills the pipeline arrays to scratch (R6: WRITE +88MB, FETCH +56MB,
//   128 us). Conclusion: register pipelines are unholdable at this occupancy.
// R7 (this): global_load_lds staging - the load has NO dest VGPR, so nothing
//   can be sunk or spilled. Each wave fires 4 x 1KB row-stages back-to-back
//   (4KB in flight vs 1KB before), one vmcnt(0) drain at the barrier (wanted
//   here), compute reads LDS via canonical stride-16B ds_read_b128 x3.
//   Block-internal halo is free in LDS; block-edge lanes redirect their read
//   address to small staged halo slots. LDS 16.6KB -> 8 blocks/CU, full
//   occupancy; 8192 blocks = 32/CU queued -> backfill smooths tails.
// Verification hooks: LDS_Block_Size ~16640, VGPR ~40, WRITE back to 131072KB.

#define B_ROWS 8192
#define C_CH   4096
#define ROWS   4       // rows staged per block
#define NCHK   256     // float4 chunks per block (1024 channels)

typedef unsigned int u32;

__global__ __launch_bounds__(256, 8) void grouped_linear_kernel(
    const float* __restrict__ x, const float* __restrict__ W,
    const float* __restrict__ bias, float* __restrict__ out)
{
    __shared__ __align__(16) float lds_rows[ROWS][1024];
    __shared__ __align__(16) float lds_haloL[ROWS][4];  // [2],[3] = x[row][blk-2..blk-1]
    __shared__ __align__(16) float lds_haloR[ROWS][4];  // [0],[1] = x[row][blk+1024..+1025]

    const int tid   = threadIdx.x;
    const int bx    = blockIdx.x;              // 0..3
    const int r0    = blockIdx.y * ROWS;
    const int chunk = bx * NCHK + tid;         // global float4 index in row
    const int c     = chunk << 2;              // base channel

    // --- loop-invariant: W rows c..c+3 (20 contiguous floats) + bias ---
    const float4* W4 = (const float4*)(W + (size_t)c * 5);
    const float4 w0 = W4[0];  // W[c][0..3]
    const float4 w1 = W4[1];  // W[c][4], W[c+1][0..2]
    const float4 w2 = W4[2];  // W[c+1][3..4], W[c+2][0..1]
    const float4 w3 = W4[3];  // W[c+2][2..4], W[c+3][0]
    const float4 w4 = W4[4];  // W[c+3][1..4]
    const float4 bv = ((const float4*)bias)[chunk];

    // ---- stage ROWS x 4KB row-slices into LDS, no dest VGPRs, no stalls ----
    {
        const int wave = tid >> 6;
        const float* gsrc0 = x + (size_t)r0 * C_CH + bx * 1024 + tid * 4;
        #pragma unroll
        for (int r = 0; r < ROWS; ++r) {
            const float* gsrc = gsrc0 + r * C_CH;
            float* ldst = &lds_rows[r][wave * 256];   // wave-uniform base + lane*16B
            __builtin_amdgcn_global_load_lds(
                (const __attribute__((address_space(1))) u32*)gsrc,
                (__attribute__((address_space(3))) u32*)ldst,
                16, 0, 0);
        }
    }

    // ---- block-edge halos: 2 float2 per row, staged by threads 0..2*ROWS-1 ----
    if (tid < 2 * ROWS) {
        const int  hr    = tid >> 1;
        const int  right = tid & 1;
        const int  gc    = bx * 1024 + (right ? 1024 : -2);  // first channel of float2
        float2 v = make_float2(0.f, 0.f);
        if (gc >= 0 && gc + 1 < C_CH)
            v = *(const float2*)(x + (size_t)(r0 + hr) * C_CH + gc);
        float* dst = right ? &lds_haloR[hr][0] : &lds_haloL[hr][2];
        *(float2*)dst = v;
    }

    __syncthreads();   // drains vmcnt(0): all 16 staged KB + halos resident

    float4* obase = (float4*)(out + (size_t)r0 * C_CH) + chunk;
    const int f = tid * 4;   // local float index of this thread's window center

    #pragma unroll
    for (int r = 0; r < ROWS; ++r) {
        const float* rowp = lds_rows[r];
        // Edge lanes redirect the read ADDRESS to the halo slot; payload lanes
        // read the canonical stride-16B pattern (full-BW ds_read_b128).
        const float4 pm = (tid > 0)
            ? *(const float4*)(rowp + f - 4)
            : *(const float4*)lds_haloL[r];        // .z,.w = win0,win1
        const float4 pc = *(const float4*)(rowp + f);
        const float4 pp = (tid < NCHK - 1)
            ? *(const float4*)(rowp + f + 4)
            : *(const float4*)lds_haloR[r];        // .x,.y = win6,win7

        // win[m] = x[r, c - 2 + m], m = 0..7
        const float win0 = pm.z, win1 = pm.w;
        const float win2 = pc.x, win3 = pc.y, win4 = pc.z, win5 = pc.w;
        const float win6 = pp.x, win7 = pp.y;

        float4 o;
        o.x = fmaf(w0.x, win0, fmaf(w0.y, win1, fmaf(w0.z, win2, fmaf(w0.w, win3, fmaf(w1.x, win4, bv.x)))));
        o.y = fmaf(w1.y, win1, fmaf(w1.z, win2, fmaf(w1.w, win3, fmaf(w2.x, win4, fmaf(w2.y, win5, bv.y)))));
        o.z = fmaf(w2.z, win2, fmaf(w2.w, win3, fmaf(w3.x, win4, fmaf(w3.y, win5, fmaf(w3.z, win6, bv.z)))));
        o.w = fmaf(w3.w, win3, fmaf(w4.x, win4, fmaf(w4.y, win5, fmaf(w4.z, win6, fmaf(w4.w, win7, bv.w)))));

        obase[r * (C_CH / 4)] = o;
    }
}

extern "C" void kernel_launch(void* const* d_in, const int* in_sizes, int n_in,
                              void* d_out, int out_size, void* d_ws, size_t ws_size,
                              hipStream_t stream) {
    const float* x    = (const float*)d_in[0];
    const float* W    = (const float*)d_in[1];
    const float* bias = (const float*)d_in[2];
    float* out = (float*)d_out;

    dim3 grid(C_CH / 1024, B_ROWS / ROWS);   // (4, 2048) = 8192 blocks
    dim3 block(256);
    grouped_linear_kernel<<<grid, block, 0, stream>>>(x, W, bias, out);
}